// Round 3
// baseline (280.274 us; speedup 1.0000x reference)
//
#include <hip/hip_runtime.h>
#include <stdint.h>

// GroupASL: out[b,g,k] = <h[b,g,:]/||h||, W[g,:,k]/||W col||>
// B=512, G=100, D=768, K=100. All f32 in/out; bf16 MFMA inside.

#define G_   100
#define D_   768
#define K_   100
#define B_   512
#define KPAD 112   // N padded to 7*16
#define BM   64    // M tile (4 waves x 16 rows)
#define BK   32    // K step (mfma 16x16x32)
#define LDP  40    // LDS row stride in bf16 elems (32 + 8 pad -> 2-way banks)

typedef __attribute__((ext_vector_type(8))) short bf16x8;
typedef __attribute__((ext_vector_type(4))) float f32x4;

__device__ __forceinline__ short f2bf(float f) {
    // round-to-nearest-even f32 -> bf16 (data is finite, no NaN handling needed)
    uint32_t u = __builtin_bit_cast(uint32_t, f);
    u = (u + 0x7FFFu + ((u >> 16) & 1u)) >> 16;
    return (short)u;
}

// ---------------- Kernel 1: partial sum-of-squares of W columns ----------------
// W[g][d][k]; each block handles (g, 128-row d-chunk), coalesced over k.
__global__ __launch_bounds__(256) void wnorm_part(const float* __restrict__ W,
                                                  float* __restrict__ wpart) {
    int bid = blockIdx.x;          // g*6 + dc
    int g = bid / 6, dc = bid % 6;
    int t = threadIdx.x;
    int k = t & 127;
    float ss = 0.f;
    if (k < K_) {
        const float* p = W + ((size_t)(g * D_ + dc * 128 + (t >> 7))) * K_ + k;
        #pragma unroll 4
        for (int i = 0; i < 64; ++i) {
            float v = p[(size_t)(2 * i) * K_];
            ss += v * v;
        }
    }
    __shared__ float red[128];
    if (t < 128) red[t] = ss;
    __syncthreads();
    if (t >= 128) red[t - 128] += ss;
    __syncthreads();
    if (t < K_) wpart[(g * 6 + dc) * K_ + t] = red[t];
}

// ---------------- Kernel 2: normalize + transpose + cast W -> Wt bf16 ----------------
// Wt[g][kp][d] (kp in [0,112), rows >= K_ are zeros). Block = (g, 64-row d-chunk).
__global__ __launch_bounds__(256) void wprep(const float* __restrict__ W,
                                             const float* __restrict__ wpart,
                                             short* __restrict__ Wt) {
    int bid = blockIdx.x;          // g*12 + dc
    int g = bid / 12, dc = bid % 12;
    int d0 = dc * 64;
    int t = threadIdx.x;
    __shared__ float tile[64][105];   // stride 105 -> 2-way banks on transposed read
    __shared__ float invn[K_];

    for (int s = t; s < 64 * 25; s += 256) {       // 64 rows x 25 float4
        int d = s / 25, j = s % 25;
        const float4 v = *(const float4*)(W + ((size_t)(g * D_ + d0 + d)) * K_ + j * 4);
        tile[d][j * 4 + 0] = v.x; tile[d][j * 4 + 1] = v.y;
        tile[d][j * 4 + 2] = v.z; tile[d][j * 4 + 3] = v.w;
    }
    if (t < K_) {
        float ss = 0.f;
        #pragma unroll
        for (int c = 0; c < 6; ++c) ss += wpart[(g * 6 + c) * K_ + t];
        invn[t] = 1.f / fmaxf(sqrtf(ss), 1e-12f);
    }
    __syncthreads();

    for (int s = t; s < KPAD * 8; s += 256) {      // 112 k-rows x 8 chunks of 8 d
        int k = s >> 3, j = s & 7;
        bf16x8 o;
        if (k < K_) {
            float inv = invn[k];
            #pragma unroll
            for (int i = 0; i < 8; ++i) o[i] = f2bf(tile[j * 8 + i][k] * inv);
        } else {
            #pragma unroll
            for (int i = 0; i < 8; ++i) o[i] = 0;
        }
        *(bf16x8*)(Wt + ((size_t)(g * KPAD + k)) * D_ + d0 + j * 8) = o;
    }
}

// ---------------- Kernel 3: per-group GEMM with fused h-normalization ----------------
// block = (g, m-tile of 64). 4 waves, each computes 16 rows x 112 cols.
__global__ __launch_bounds__(256) void gemm(const float* __restrict__ h,
                                            const short* __restrict__ Wt,
                                            float* __restrict__ out) {
    int bid = blockIdx.x;          // g*8 + mt (consecutive blocks share g -> L2 reuse of Wt)
    int g = bid >> 3, mt = bid & 7;
    int b0 = mt * BM;
    int t = threadIdx.x;
    int wave = t >> 6, lane = t & 63;

    __shared__ __align__(16) short As[BM * LDP];
    __shared__ __align__(16) short Bs[KPAD * LDP];
    __shared__ float hss[BM];

    int ar = t >> 2, aq = t & 3;   // A staging: row (0..63), 8-float chunk (0..3)
    const float* hp = h + ((size_t)(b0 + ar) * G_ + g) * D_ + aq * 8;
    const short* wtg = Wt + (size_t)g * KPAD * D_;

    f32x4 acc[7];
    #pragma unroll
    for (int i = 0; i < 7; ++i) acc[i] = (f32x4){0.f, 0.f, 0.f, 0.f};
    float ss = 0.f;

    for (int kt = 0; kt < D_ / BK; ++kt) {
        __syncthreads();
        // stage A (f32 -> bf16, fused row-sumsq)
        {
            const float* p = hp + kt * BK;
            float4 v0 = *(const float4*)(p);
            float4 v1 = *(const float4*)(p + 4);
            float vs[8] = {v0.x, v0.y, v0.z, v0.w, v1.x, v1.y, v1.z, v1.w};
            bf16x8 o;
            #pragma unroll
            for (int i = 0; i < 8; ++i) { ss += vs[i] * vs[i]; o[i] = f2bf(vs[i]); }
            *(bf16x8*)(As + ar * LDP + aq * 8) = o;
        }
        // stage B (already bf16, contiguous over d)
        for (int s = t; s < KPAD * 4; s += 256) {
            int n = s >> 2, j = s & 3;
            bf16x8 v = *(const bf16x8*)(wtg + (size_t)n * D_ + kt * BK + j * 8);
            *(bf16x8*)(Bs + n * LDP + j * 8) = v;
        }
        __syncthreads();

        int frow = lane & 15, fk = (lane >> 4) * 8;
        bf16x8 a = *(const bf16x8*)(As + (wave * 16 + frow) * LDP + fk);
        #pragma unroll
        for (int nt = 0; nt < 7; ++nt) {
            bf16x8 b = *(const bf16x8*)(Bs + (nt * 16 + frow) * LDP + fk);
            acc[nt] = __builtin_amdgcn_mfma_f32_16x16x32_bf16(a, b, acc[nt], 0, 0, 0);
        }
    }

    // reduce per-row sumsq (4 staging threads per row live in the same wave)
    ss += __shfl_xor(ss, 1);
    ss += __shfl_xor(ss, 2);
    if (aq == 0) hss[ar] = ss;
    __syncthreads();

    // epilogue: C/D layout col=lane&15, row=(lane>>4)*4+reg  [verified m89]
    int col = lane & 15;
    int rbase = wave * 16 + (lane >> 4) * 4;
    float invh[4];
    #pragma unroll
    for (int r = 0; r < 4; ++r) invh[r] = 1.f / fmaxf(sqrtf(hss[rbase + r]), 1e-12f);
    #pragma unroll
    for (int nt = 0; nt < 7; ++nt) {
        int n = nt * 16 + col;
        if (n < K_) {
            #pragma unroll
            for (int r = 0; r < 4; ++r) {
                int b = b0 + rbase + r;
                out[((size_t)b * G_ + g) * K_ + n] = acc[nt][r] * invh[r];
            }
        }
    }
}

extern "C" void kernel_launch(void* const* d_in, const int* in_sizes, int n_in,
                              void* d_out, int out_size, void* d_ws, size_t ws_size,
                              hipStream_t stream) {
    const float* h = (const float*)d_in[0];
    const float* W = (const float*)d_in[1];
    // d_in[2] (out_extrap) is unused by the reference math.
    float* out = (float*)d_out;

    short* Wt = (short*)d_ws;                                        // 100*112*768*2 = 17.2 MB
    float* wpart = (float*)((char*)d_ws + (size_t)G_ * KPAD * D_ * 2); // +240 KB

    wnorm_part<<<dim3(G_ * 6),  dim3(256), 0, stream>>>(W, wpart);
    wprep     <<<dim3(G_ * 12), dim3(256), 0, stream>>>(W, wpart, Wt);
    gemm      <<<dim3(G_ * 8),  dim3(256), 0, stream>>>(h, Wt, out);
}